// Round 2
// baseline (10987.048 us; speedup 1.0000x reference)
//
#include <hip/hip_runtime.h>
#include <hip/hip_fp16.h>

#define B_ 32
#define T_ 4096
#define F_ 128
#define C_ 256
#define K_ 128
#define FC_ 384

typedef __attribute__((ext_vector_type(8))) short s8v;
typedef __attribute__((ext_vector_type(4))) float f4v;

#define MFMA16(a,b,c) __builtin_amdgcn_mfma_f32_16x16x32_bf16((a),(b),(c),0,0,0)

// ---- workspace layout (bytes) ----
// fixed region:
#define WS_WSCAN 0u        // 16384 B-frags * 16B = 262144
#define WS_W1F   262144u   // 12288 * 16 = 196608
#define WS_OWF   458752u   // 4096 * 16 = 65536
#define WS_BIAS1 524288u   // 768 * 4 = 3072
#define WS_CARRY 527360u   // n,d,h,am : 4 * 8192 f32 = 131072
#define WS_DYN   658432u   // pre chunk (49152*Tc B) then hall chunk (16384*Tc B)

__device__ __forceinline__ unsigned short f2bf(float f){
  unsigned u = __float_as_uint(f);
  u += 0x7fffu + ((u>>16)&1u);     // round-to-nearest-even
  return (unsigned short)(u>>16);
}
__device__ __forceinline__ float ftanh(float x){
  float xc = fminf(fmaxf(x,-9.02f),9.02f);
  float e = __expf(2.0f*xc);
  return 1.0f - 2.0f*__builtin_amdgcn_rcpf(e+1.0f);
}

// ---------------- weight packing into MFMA B-frag layouts ----------------
// B-frag (16x16x32): lane l, reg j holds B[k = kc*32 + (l>>4)*8 + j][n = 16*nt + (l&15)]
__global__ __launch_bounds__(256) void pack_kernel(
    const float* __restrict__ g_w, const float* __restrict__ u_w, const float* __restrict__ a_w,
    const float* __restrict__ g_b, const float* __restrict__ u_b, const float* __restrict__ o_w,
    char* __restrict__ ws)
{
  int id = blockIdx.x*256 + threadIdx.x;
  unsigned short* wscan = (unsigned short*)(ws + WS_WSCAN);
  unsigned short* w1f   = (unsigned short*)(ws + WS_W1F);
  unsigned short* owf   = (unsigned short*)(ws + WS_OWF);
  float* bias1          = (float*)(ws + WS_BIAS1);
  if (id < 16384){
    // scan weights: idx = (((w*2+mat)*2+tp)*8+kc)*64 + lane ; value = W[c][128+k]
    int l = id & 63, kc = (id>>6)&7, tp = (id>>9)&1, mat = (id>>10)&1, w = id>>11;
    int c  = w*32 + tp*16 + (l&15);
    int kb = kc*32 + (l>>4)*8;
    const float* src = mat ? a_w : g_w;
    #pragma unroll
    for (int j=0;j<8;++j)
      wscan[id*8+j] = f2bf(src[c*FC_ + F_ + kb + j]);
  } else if (id < 16384+12288){
    // ph1 weights rows n: [0,256)=u_w, [256,512)=g_w x-part, [512,768)=a_w x-part
    int id2 = id - 16384;
    int l = id2 & 63, kc = (id2>>6)&3, nt = id2>>8;
    int n = nt*16 + (l&15);
    int kb = kc*32 + (l>>4)*8;
    #pragma unroll
    for (int j=0;j<8;++j){
      int k = kb + j;
      float v = (n < 256) ? u_w[n*F_ + k]
              : (n < 512) ? g_w[(n-256)*FC_ + k]
                          : a_w[(n-512)*FC_ + k];
      w1f[id2*8+j] = f2bf(v);
    }
  } else if (id < 16384+12288+4096){
    int id3 = id - (16384+12288);
    int l = id3 & 63, kc = (id3>>6)&7, nt = id3>>9;
    int n = nt*16 + (l&15);
    int kb = kc*32 + (l>>4)*8;
    #pragma unroll
    for (int j=0;j<8;++j)
      owf[id3*8+j] = f2bf(o_w[n*C_ + kb + j]);
  } else if (id < 16384+12288+4096+768){
    int i = id - (16384+12288+4096);
    bias1[i] = (i<256) ? u_b[i] : (i<512 ? g_b[i-256] : 0.0f);
  }
}

// ---------------- init: carry <- initial state ----------------
__global__ __launch_bounds__(256) void init_kernel(
    const float* __restrict__ n0, const float* __restrict__ d0,
    const float* __restrict__ h0, const float* __restrict__ am0, char* __restrict__ ws)
{
  int id = blockIdx.x*256 + threadIdx.x;   // 8192
  float* c = (float*)(ws + WS_CARRY);
  c[id]        = n0[id];
  c[8192+id]   = d0[id];
  c[16384+id]  = h0[id];
  c[24576+id]  = am0[id];
}

// ---------------- ph1: pre = x @ [u_w; g_w_x; a_w_x]^T + bias (fp16, chunk-local) --------
__global__ __launch_bounds__(256) void ph1_kernel(const float* __restrict__ x, char* __restrict__ ws,
                                                  int t0, int Tc, int lgT16)
{
  const s8v* w1f = (const s8v*)(ws + WS_W1F);
  const float* bias1 = (const float*)(ws + WS_BIAS1);
  __half* pre = (__half*)(ws + WS_DYN);
  int tid = threadIdx.x;
  int wv = tid>>6, l = tid&63, q = l>>4, col = l&15;
  int wid = blockIdx.x*4 + wv;
  int b  = wid >> lgT16;
  int tb = (wid & ((1<<lgT16)-1))*16;
  // A-frag: lane holds x[b][t0+tb+(l&15)][kc*32 + q*8 + j]
  s8v af[4];
  const float* xr = x + ((size_t)b*T_ + t0 + tb + col)*F_ + q*8;
  #pragma unroll
  for (int kc=0;kc<4;++kc){
    const float* p = xr + kc*32;
    float4 p0 = *(const float4*)(p);
    float4 p1 = *(const float4*)(p+4);
    s8v a;
    a[0]=(short)f2bf(p0.x); a[1]=(short)f2bf(p0.y); a[2]=(short)f2bf(p0.z); a[3]=(short)f2bf(p0.w);
    a[4]=(short)f2bf(p1.x); a[5]=(short)f2bf(p1.y); a[6]=(short)f2bf(p1.z); a[7]=(short)f2bf(p1.w);
    af[kc]=a;
  }
  for (int nt=0;nt<48;++nt){
    f4v acc = {0.f,0.f,0.f,0.f};
    #pragma unroll
    for (int kc=0;kc<4;++kc)
      acc = MFMA16(af[kc], w1f[(nt*4+kc)*64 + l], acc);
    int cg = nt*16 + col;
    float bs = bias1[cg];
    #pragma unroll
    for (int i=0;i<4;++i){
      int rl = tb + q*4 + i;                 // D: row = (l>>4)*4 + i
      pre[(size_t)(b*Tc + rl)*768 + cg] = __float2half(acc[i] + bs);
    }
  }
}

// ---------------- scan: the sequential recurrence over one chunk ----------------
// 2 blocks x 512 threads; block handles 16 batch rows; wave w owns c-strip [32w,32w+32).
__global__ __launch_bounds__(512,2) void scan_kernel(char* __restrict__ ws, int Tc)
{
  __shared__ __align__(16) unsigned short hbuf[2][16][264];
  const s8v* wp = (const s8v*)(ws + WS_WSCAN);
  const __half* pre = (const __half*)(ws + WS_DYN);
  unsigned short* hall = (unsigned short*)(ws + WS_DYN + 49152u*(unsigned)Tc);
  float* carry = (float*)(ws + WS_CARRY);
  int tid = threadIdx.x;
  int w = tid>>6, l = tid&63, q = l>>4, col = l&15;
  int b0 = blockIdx.x*16;

  // resident weights: 32 B-frags = 128 VGPRs
  s8v wg[2][8], wa[2][8];
  #pragma unroll
  for (int tp=0;tp<2;++tp)
    #pragma unroll
    for (int kc=0;kc<8;++kc){
      wg[tp][kc] = wp[(((w*2+0)*2+tp)*8+kc)*64 + l];
      wa[tp][kc] = wp[(((w*2+1)*2+tp)*8+kc)*64 + l];
    }

  // carry: lane owns (b = b0+q*4+i, c = 32w+16tp+col)
  float cn[4][2], cd[4][2], cm[4][2];
  #pragma unroll
  for (int i=0;i<4;++i)
    #pragma unroll
    for (int tp=0;tp<2;++tp){
      int m = q*4+i, c = w*32+tp*16+col;
      int gi = (b0+m)*C_ + c;
      cn[i][tp]=carry[gi]; cd[i][tp]=carry[8192+gi]; cm[i][tp]=carry[24576+gi];
      hbuf[0][m][c] = f2bf(carry[16384+gi]);
    }
  __syncthreads();

  unsigned short* hc = &hbuf[0][0][0];
  unsigned short* hn = &hbuf[1][0][0];

  #pragma unroll 1
  for (int t=0;t<Tc;++t){
    // prefetch x-precomputed values
    float pu[4][2], pg[4][2], pa[4][2];
    #pragma unroll
    for (int i=0;i<4;++i)
      #pragma unroll
      for (int tp=0;tp<2;++tp){
        int m=q*4+i, c=w*32+tp*16+col;
        const __half* pr = pre + ((size_t)(b0+m)*Tc + t)*768;
        pu[i][tp]=__half2float(pr[c]);
        pg[i][tp]=__half2float(pr[256+c]);
        pa[i][tp]=__half2float(pr[512+c]);
      }
    // h-part matmul: [16,256] x [256,512]
    f4v z4 = {0.f,0.f,0.f,0.f};
    f4v aG[2], aA[2];
    aG[0]=z4; aG[1]=z4; aA[0]=z4; aA[1]=z4;
    #pragma unroll
    for (int kc=0;kc<8;++kc){
      s8v af = *(const s8v*)(hc + col*264 + kc*32 + q*8);
      aG[0]=MFMA16(af,wg[0][kc],aG[0]);
      aG[1]=MFMA16(af,wg[1][kc],aG[1]);
      aA[0]=MFMA16(af,wa[0][kc],aA[0]);
      aA[1]=MFMA16(af,wa[1][kc],aA[1]);
    }
    // lane-local elementwise update
    size_t tilebase = ((size_t)blockIdx.x*Tc + t)*4096;
    #pragma unroll
    for (int tp=0;tp<2;++tp){
      unsigned lo=0, hi=0;
      #pragma unroll
      for (int i=0;i<4;++i){
        float g = aG[tp][i] + pg[i][tp];
        float a = aA[tp][i] + pa[i][tp];
        float z = pu[i][tp]*ftanh(g);
        float am = cm[i][tp];
        float anew = fmaxf(am,a);
        float dmin = fminf(am,a);
        float e = __expf(dmin-anew);        // one of exp_diff/exp_scaled is exp(0)=1
        bool ge = (a>=am);
        float ed = ge? e : 1.0f;
        float es = ge? 1.0f : e;
        float nn = cn[i][tp]*ed + z*es;
        float dd = fmaf(cd[i][tp],ed,es);
        float hv = ftanh(nn*__builtin_amdgcn_rcpf(dd));
        cn[i][tp]=nn; cd[i][tp]=dd; cm[i][tp]=anew;
        unsigned short hs = f2bf(hv);
        int m=q*4+i, c=w*32+tp*16+col;
        hn[m*264+c]=hs;                     // next step's A tile
        if (i<2) lo |= ((unsigned)hs)<<(16*i);
        else     hi |= ((unsigned)hs)<<(16*(i-2));
        if (t==Tc-1){
          int gi=(b0+m)*C_+c;
          carry[gi]=nn; carry[8192+gi]=dd; carry[16384+gi]=hv; carry[24576+gi]=anew;
        }
      }
      int c = w*32+tp*16+col;
      uint2 pk; pk.x=lo; pk.y=hi;
      *(uint2*)(hall + tilebase + c*16 + q*4) = pk;   // h^T tile [c][m], m=q*4..q*4+3
    }
    __syncthreads();
    unsigned short* tmp=hc; hc=hn; hn=tmp;
  }
}

// ---------------- ph3: outs = h @ o_w^T + o_b  (one wave per (bblk,t) tile) ----------------
__global__ __launch_bounds__(256) void ph3_kernel(const float* __restrict__ o_b,
                                                  char* __restrict__ ws, float* __restrict__ out,
                                                  int t0, int Tc, int lgTc)
{
  __shared__ __align__(16) unsigned short hh[4][16][264];
  const s8v* owf = (const s8v*)(ws + WS_OWF);
  const unsigned short* hall = (const unsigned short*)(ws + WS_DYN + 49152u*(unsigned)Tc);
  int tid = threadIdx.x;
  int wv = tid>>6, l = tid&63, q=l>>4, col=l&15;
  int wid = blockIdx.x*4 + wv;
  int bblk = wid >> lgTc;
  int tl   = wid & (Tc-1);
  // load h^T tile [c][m] -> LDS h[m][c]
  const unsigned short* src = hall + (size_t)wid*4096;
  int m0 = (l&1)*8, cb = l>>1;
  #pragma unroll
  for (int j=0;j<8;++j){
    s8v v = *(const s8v*)(src + l*8 + j*512);
    int c = cb + j*32;
    #pragma unroll
    for (int mm=0;mm<8;++mm)
      hh[wv][m0+mm][c] = (unsigned short)v[mm];
  }
  __syncthreads();
  s8v af[8];
  #pragma unroll
  for (int kc=0;kc<8;++kc)
    af[kc] = *(const s8v*)(&hh[wv][col][kc*32+q*8]);
  #pragma unroll
  for (int nt=0;nt<8;++nt){
    f4v acc={0.f,0.f,0.f,0.f};
    #pragma unroll
    for (int kc=0;kc<8;++kc)
      acc = MFMA16(af[kc], owf[(nt*8+kc)*64 + l], acc);
    int k = nt*16+col;
    float bs = o_b[k];
    #pragma unroll
    for (int i=0;i<4;++i){
      int b = bblk*16 + q*4 + i;
      out[((size_t)b*T_ + t0 + tl)*K_ + k] = acc[i] + bs;
    }
  }
}

// ---------------- finalize: final states -> out tail ----------------
__global__ __launch_bounds__(256) void fin_kernel(char* __restrict__ ws, float* __restrict__ out)
{
  int id = blockIdx.x*256 + threadIdx.x;   // 8192
  const float* c = (const float*)(ws + WS_CARRY);
  size_t ob = (size_t)B_*T_*K_;
  out[ob + id]         = c[id];            // n_t
  out[ob + 8192 + id]  = c[8192+id];       // d_t
  out[ob + 16384 + id] = c[16384+id];      // h_t
  out[ob + 24576 + id] = c[24576+id];      // a_new
}

extern "C" void kernel_launch(void* const* d_in, const int* in_sizes, int n_in,
                              void* d_out, int out_size, void* d_ws, size_t ws_size,
                              hipStream_t stream)
{
  const float* x   = (const float*)d_in[0];
  const float* n0  = (const float*)d_in[1];
  const float* d0  = (const float*)d_in[2];
  const float* h0  = (const float*)d_in[3];
  const float* am0 = (const float*)d_in[4];
  const float* g_w = (const float*)d_in[5];
  const float* g_b = (const float*)d_in[6];
  const float* u_w = (const float*)d_in[7];
  const float* u_b = (const float*)d_in[8];
  const float* a_w = (const float*)d_in[9];
  const float* o_w = (const float*)d_in[10];
  const float* o_b = (const float*)d_in[11];
  float* out = (float*)d_out;
  char* ws = (char*)d_ws;

  // pick largest power-of-two time chunk Tc that fits: fixed + (49152+16384)*Tc bytes
  unsigned Tc = 4096;
  while (Tc > 64 && (size_t)WS_DYN + 65536ull*Tc > ws_size) Tc >>= 1;
  if ((size_t)WS_DYN + 65536ull*Tc > ws_size) return;  // ws hopeless -> zeros (diagnosable)
  int lgTc  = __builtin_ctz(Tc);
  int lgT16 = lgTc - 4;
  int nch   = T_ / (int)Tc;

  hipLaunchKernelGGL(pack_kernel, dim3(131), dim3(256), 0, stream,
                     g_w, u_w, a_w, g_b, u_b, o_w, ws);
  hipLaunchKernelGGL(init_kernel, dim3(32), dim3(256), 0, stream,
                     n0, d0, h0, am0, ws);
  for (int c0=0; c0<nch; ++c0){
    int t0 = c0*(int)Tc;
    hipLaunchKernelGGL(ph1_kernel, dim3(B_*(int)Tc/64), dim3(256), 0, stream,
                       x, ws, t0, (int)Tc, lgT16);
    hipLaunchKernelGGL(scan_kernel, dim3(2), dim3(512), 0, stream,
                       ws, (int)Tc);
    hipLaunchKernelGGL(ph3_kernel, dim3(2*(int)Tc/4), dim3(256), 0, stream,
                       o_b, ws, out, t0, (int)Tc, lgTc);
  }
  hipLaunchKernelGGL(fin_kernel, dim3(32), dim3(256), 0, stream, ws, out);
}

// Round 3
// 4514.084 us; speedup vs baseline: 2.4339x; 2.4339x over previous
//
#include <hip/hip_runtime.h>
#include <hip/hip_fp16.h>

#define B_ 32
#define T_ 4096
#define F_ 128
#define C_ 256
#define K_ 128
#define FC_ 384

typedef __attribute__((ext_vector_type(8))) short s8v;
typedef __attribute__((ext_vector_type(4))) float f4v;

#define MFMA16(a,b,c) __builtin_amdgcn_mfma_f32_16x16x32_bf16((a),(b),(c),0,0,0)

// ---- workspace layout (bytes) ----
#define WS_WSCAN 0u        // 16384 B-frags * 16B = 262144
#define WS_W1F   262144u   // 12288 * 16 = 196608
#define WS_OWF   458752u   // 4096 * 16 = 65536
#define WS_BIAS1 524288u   // 768 * 4 = 3072
#define WS_CARRY 527360u   // n,d,h,am : 4 * 8192 f32 = 131072
#define WS_DYN   658432u   // pre chunk (49152*Tc B) then hall chunk (16384*Tc B)

__device__ __forceinline__ unsigned short f2bf(float f){
  unsigned u = __float_as_uint(f);
  u += 0x7fffu + ((u>>16)&1u);     // round-to-nearest-even
  return (unsigned short)(u>>16);
}
__device__ __forceinline__ float h2f(unsigned short s){
  __half_raw r; r.x = s; return __half2float((__half)r);
}
__device__ __forceinline__ float ftanh(float x){
  float xc = fminf(fmaxf(x,-9.02f),9.02f);
  float e = __expf(2.0f*xc);
  return 1.0f - 2.0f*__builtin_amdgcn_rcpf(e+1.0f);
}

// ---------------- weight packing into MFMA B-frag layouts ----------------
// B-frag (16x16x32): lane l, reg j holds B[k = kc*32 + (l>>4)*8 + j][n = 16*nt + (l&15)]
__global__ __launch_bounds__(256) void pack_kernel(
    const float* __restrict__ g_w, const float* __restrict__ u_w, const float* __restrict__ a_w,
    const float* __restrict__ g_b, const float* __restrict__ u_b, const float* __restrict__ o_w,
    char* __restrict__ ws)
{
  int id = blockIdx.x*256 + threadIdx.x;
  unsigned short* wscan = (unsigned short*)(ws + WS_WSCAN);
  unsigned short* w1f   = (unsigned short*)(ws + WS_W1F);
  unsigned short* owf   = (unsigned short*)(ws + WS_OWF);
  float* bias1          = (float*)(ws + WS_BIAS1);
  if (id < 16384){
    // scan weights: idx = (((wv*2+mat)*4+tp)*8+kc)*64 + lane ; value = W[c][128+k]
    // wave wv owns channels [64wv, 64wv+64): c = 64wv + 16tp + (l&15)
    int l = id & 63, kc = (id>>6)&7, tp = (id>>9)&3, mat = (id>>11)&1, wv = id>>12;
    int c  = wv*64 + tp*16 + (l&15);
    int kb = kc*32 + (l>>4)*8;
    const float* src = mat ? a_w : g_w;
    #pragma unroll
    for (int j=0;j<8;++j)
      wscan[id*8+j] = f2bf(src[c*FC_ + F_ + kb + j]);
  } else if (id < 16384+12288){
    // ph1 weights rows n: [0,256)=u_w, [256,512)=g_w x-part, [512,768)=a_w x-part
    int id2 = id - 16384;
    int l = id2 & 63, kc = (id2>>6)&3, nt = id2>>8;
    int n = nt*16 + (l&15);
    int kb = kc*32 + (l>>4)*8;
    #pragma unroll
    for (int j=0;j<8;++j){
      int k = kb + j;
      float v = (n < 256) ? u_w[n*F_ + k]
              : (n < 512) ? g_w[(n-256)*FC_ + k]
                          : a_w[(n-512)*FC_ + k];
      w1f[id2*8+j] = f2bf(v);
    }
  } else if (id < 16384+12288+4096){
    int id3 = id - (16384+12288);
    int l = id3 & 63, kc = (id3>>6)&7, nt = id3>>9;
    int n = nt*16 + (l&15);
    int kb = kc*32 + (l>>4)*8;
    #pragma unroll
    for (int j=0;j<8;++j)
      owf[id3*8+j] = f2bf(o_w[n*C_ + kb + j]);
  } else if (id < 16384+12288+4096+768){
    int i = id - (16384+12288+4096);
    bias1[i] = (i<256) ? u_b[i] : (i<512 ? g_b[i-256] : 0.0f);
  }
}

// ---------------- init: carry <- initial state ----------------
__global__ __launch_bounds__(256) void init_kernel(
    const float* __restrict__ n0, const float* __restrict__ d0,
    const float* __restrict__ h0, const float* __restrict__ am0, char* __restrict__ ws)
{
  int id = blockIdx.x*256 + threadIdx.x;   // 8192
  float* c = (float*)(ws + WS_CARRY);
  c[id]        = n0[id];
  c[8192+id]   = d0[id];
  c[16384+id]  = h0[id];
  c[24576+id]  = am0[id];
}

// ---------------- ph1: pre = x @ [u_w; g_w_x; a_w_x]^T + bias (fp16, chunk-local) --------
__global__ __launch_bounds__(256) void ph1_kernel(const float* __restrict__ x, char* __restrict__ ws,
                                                  int t0, int Tc, int lgT16)
{
  const s8v* w1f = (const s8v*)(ws + WS_W1F);
  const float* bias1 = (const float*)(ws + WS_BIAS1);
  __half* pre = (__half*)(ws + WS_DYN);
  int tid = threadIdx.x;
  int wv = tid>>6, l = tid&63, q = l>>4, col = l&15;
  int wid = blockIdx.x*4 + wv;
  int b  = wid >> lgT16;
  int tb = (wid & ((1<<lgT16)-1))*16;
  // A-frag: lane holds x[b][t0+tb+(l&15)][kc*32 + q*8 + j]
  s8v af[4];
  const float* xr = x + ((size_t)b*T_ + t0 + tb + col)*F_ + q*8;
  #pragma unroll
  for (int kc=0;kc<4;++kc){
    const float* p = xr + kc*32;
    float4 p0 = *(const float4*)(p);
    float4 p1 = *(const float4*)(p+4);
    s8v a;
    a[0]=(short)f2bf(p0.x); a[1]=(short)f2bf(p0.y); a[2]=(short)f2bf(p0.z); a[3]=(short)f2bf(p0.w);
    a[4]=(short)f2bf(p1.x); a[5]=(short)f2bf(p1.y); a[6]=(short)f2bf(p1.z); a[7]=(short)f2bf(p1.w);
    af[kc]=a;
  }
  for (int nt=0;nt<48;++nt){
    f4v acc = {0.f,0.f,0.f,0.f};
    #pragma unroll
    for (int kc=0;kc<4;++kc)
      acc = MFMA16(af[kc], w1f[(nt*4+kc)*64 + l], acc);
    int cg = nt*16 + col;
    float bs = bias1[cg];
    #pragma unroll
    for (int i=0;i<4;++i){
      int rl = tb + q*4 + i;                 // D: row = (l>>4)*4 + i
      pre[(size_t)(b*Tc + rl)*768 + cg] = __float2half(acc[i] + bs);
    }
  }
}

// ---------------- scan: sequential recurrence, 1 batch row per block ----------------
// 32 blocks x 256 threads (4 waves, 1 wave/SIMD). A-tile = h replicated over all 16 M rows
// -> broadcast ds_reads, every lane owns exactly 1 channel: c = 64*wv + 16*q + col.
__global__ __launch_bounds__(256,1) void scan_kernel(char* __restrict__ ws, int Tc)
{
  __shared__ __align__(16) unsigned short hbuf[2][256];
  const s8v* wp = (const s8v*)(ws + WS_WSCAN);
  const unsigned short* prbu = (const unsigned short*)(ws + WS_DYN);
  unsigned short* hall = (unsigned short*)(ws + WS_DYN + 49152u*(unsigned)Tc);
  float* carry = (float*)(ws + WS_CARRY);
  int tid = threadIdx.x;
  int wv = tid>>6, l = tid&63, q = l>>4, col = l&15;
  int b = blockIdx.x;
  int c = wv*64 + q*16 + col;          // this lane's channel

  // resident weights: 64 B-frags = 256 VGPR/AGPR per wave
  s8v wg[4][8], wa[4][8];
  #pragma unroll
  for (int tp=0;tp<4;++tp)
    #pragma unroll
    for (int kc=0;kc<8;++kc){
      wg[tp][kc] = wp[(((wv*2+0)*4+tp)*8+kc)*64 + l];
      wa[tp][kc] = wp[(((wv*2+1)*4+tp)*8+kc)*64 + l];
    }

  int gi = b*C_ + c;
  float cn = carry[gi], cd = carry[8192+gi], cm = carry[24576+gi];
  hbuf[0][c] = f2bf(carry[16384+gi]);
  __syncthreads();

  const size_t prb = (size_t)b*Tc*768;
  unsigned short* hrow = hall + (size_t)b*Tc*C_ + c;

  // prefetch pre for t=0,1 (2-deep pipeline hides HBM latency)
  unsigned short su[2], sg[2], sa[2];
  su[0]=prbu[prb + c];       sg[0]=prbu[prb + 256+c];       sa[0]=prbu[prb + 512+c];
  su[1]=prbu[prb + 768+c];   sg[1]=prbu[prb + 768+256+c];   sa[1]=prbu[prb + 768+512+c];

  #pragma unroll 1
  for (int t=0;t<Tc;++t){
    int cur = t & 1;
    const unsigned short* hc = hbuf[cur];
    unsigned short* hn = hbuf[cur^1];
    // consume slot, then refill for t+2
    float fu = h2f(su[cur]), fg = h2f(sg[cur]), fa = h2f(sa[cur]);
    {
      int nxt = (t+2 < Tc) ? t+2 : t;
      size_t o = prb + (size_t)nxt*768;
      su[cur]=prbu[o + c]; sg[cur]=prbu[o + 256+c]; sa[cur]=prbu[o + 512+c];
    }
    // h-part matmul: [16(dup),256] x [256,512]
    f4v aG[4], aA[4];
    #pragma unroll
    for (int tp=0;tp<4;++tp){ aG[tp]=(f4v){0.f,0.f,0.f,0.f}; aA[tp]=(f4v){0.f,0.f,0.f,0.f}; }
    #pragma unroll
    for (int kc=0;kc<8;++kc){
      s8v af = *(const s8v*)(hc + kc*32 + q*8);   // broadcast across the 16 cols
      #pragma unroll
      for (int tp=0;tp<4;++tp){
        aG[tp]=MFMA16(af,wg[tp][kc],aG[tp]);
        aA[tp]=MFMA16(af,wa[tp][kc],aA[tp]);
      }
    }
    // pick this lane's channel value (D rows identical -> reg 0; select accumulator by q)
    float g01 = (q&1)? aG[1][0] : aG[0][0];
    float g23 = (q&1)? aG[3][0] : aG[2][0];
    float g = ((q&2)? g23 : g01) + fg;
    float a01 = (q&1)? aA[1][0] : aA[0][0];
    float a23 = (q&1)? aA[3][0] : aA[2][0];
    float a = ((q&2)? a23 : a01) + fa;

    float z = fu * ftanh(g);
    float anew = fmaxf(cm,a);
    float dmin = fminf(cm,a);
    float e = __expf(dmin-anew);     // one of exp_diff/exp_scaled is exp(0)=1
    bool ge = (a>=cm);
    float ed = ge? e : 1.0f;
    float es = ge? 1.0f : e;
    cn = cn*ed + z*es;
    cd = fmaf(cd,ed,es);
    float hv = ftanh(cn*__builtin_amdgcn_rcpf(cd));
    cm = anew;
    unsigned short hs = f2bf(hv);
    hn[c] = hs;
    hrow[(size_t)t*C_] = hs;
    __syncthreads();
  }
  // write back carry
  carry[gi] = cn; carry[8192+gi] = cd; carry[24576+gi] = cm;
  carry[16384+gi] = h2f(0) , carry[16384+gi] = ftanh(cn*__builtin_amdgcn_rcpf(cd)); // h_t
}

// ---------------- ph3: outs = h @ o_w^T + o_b  (one wave per (b, 16-step tile)) --------
__global__ __launch_bounds__(256) void ph3_kernel(const float* __restrict__ o_b,
                                                  char* __restrict__ ws, float* __restrict__ out,
                                                  int t0, int Tc, int lgT16)
{
  const s8v* owf = (const s8v*)(ws + WS_OWF);
  const unsigned short* hall = (const unsigned short*)(ws + WS_DYN + 49152u*(unsigned)Tc);
  int tid = threadIdx.x;
  int wv = tid>>6, l = tid&63, q=l>>4, col=l&15;
  int wid = blockIdx.x*4 + wv;
  int bb = wid >> lgT16;
  int tt = (wid & ((1<<lgT16)-1))*16;
  // A[m=col][k] = h[b=bb][t=tt+col][k]
  const unsigned short* src = hall + ((size_t)bb*Tc + tt)*C_;
  s8v af[8];
  #pragma unroll
  for (int kc=0;kc<8;++kc)
    af[kc] = *(const s8v*)(src + (size_t)col*C_ + kc*32 + q*8);
  #pragma unroll
  for (int nt=0;nt<8;++nt){
    f4v acc={0.f,0.f,0.f,0.f};
    #pragma unroll
    for (int kc=0;kc<8;++kc)
      acc = MFMA16(af[kc], owf[(nt*8+kc)*64 + l], acc);
    int k = nt*16+col;
    float bs = o_b[k];
    #pragma unroll
    for (int i=0;i<4;++i)
      out[((size_t)bb*T_ + t0 + tt + q*4 + i)*K_ + k] = acc[i] + bs;
  }
}

// ---------------- finalize: final states -> out tail ----------------
__global__ __launch_bounds__(256) void fin_kernel(char* __restrict__ ws, float* __restrict__ out)
{
  int id = blockIdx.x*256 + threadIdx.x;   // 8192
  const float* c = (const float*)(ws + WS_CARRY);
  size_t ob = (size_t)B_*T_*K_;
  out[ob + id]         = c[id];            // n_t
  out[ob + 8192 + id]  = c[8192+id];       // d_t
  out[ob + 16384 + id] = c[16384+id];      // h_t
  out[ob + 24576 + id] = c[24576+id];      // a_new
}

extern "C" void kernel_launch(void* const* d_in, const int* in_sizes, int n_in,
                              void* d_out, int out_size, void* d_ws, size_t ws_size,
                              hipStream_t stream)
{
  const float* x   = (const float*)d_in[0];
  const float* n0  = (const float*)d_in[1];
  const float* d0  = (const float*)d_in[2];
  const float* h0  = (const float*)d_in[3];
  const float* am0 = (const float*)d_in[4];
  const float* g_w = (const float*)d_in[5];
  const float* g_b = (const float*)d_in[6];
  const float* u_w = (const float*)d_in[7];
  const float* u_b = (const float*)d_in[8];
  const float* a_w = (const float*)d_in[9];
  const float* o_w = (const float*)d_in[10];
  const float* o_b = (const float*)d_in[11];
  float* out = (float*)d_out;
  char* ws = (char*)d_ws;

  // pick largest power-of-two time chunk Tc that fits: fixed + (49152+16384)*Tc bytes
  unsigned Tc = 4096;
  while (Tc > 64 && (size_t)WS_DYN + 65536ull*Tc > ws_size) Tc >>= 1;
  if ((size_t)WS_DYN + 65536ull*Tc > ws_size) return;  // ws hopeless -> zeros (diagnosable)
  int lgTc  = __builtin_ctz(Tc);
  int lgT16 = lgTc - 4;
  int nch   = T_ / (int)Tc;

  hipLaunchKernelGGL(pack_kernel, dim3(131), dim3(256), 0, stream,
                     g_w, u_w, a_w, g_b, u_b, o_w, ws);
  hipLaunchKernelGGL(init_kernel, dim3(32), dim3(256), 0, stream,
                     n0, d0, h0, am0, ws);
  for (int c0=0; c0<nch; ++c0){
    int t0 = c0*(int)Tc;
    hipLaunchKernelGGL(ph1_kernel, dim3(B_*(int)Tc/64), dim3(256), 0, stream,
                       x, ws, t0, (int)Tc, lgT16);
    hipLaunchKernelGGL(scan_kernel, dim3(B_), dim3(256), 0, stream,
                       ws, (int)Tc);
    hipLaunchKernelGGL(ph3_kernel, dim3(B_*(int)Tc/64), dim3(256), 0, stream,
                       o_b, ws, out, t0, (int)Tc, lgT16);
  }
  hipLaunchKernelGGL(fin_kernel, dim3(32), dim3(256), 0, stream, ws, out);
}